// Round 6
// baseline (7227.094 us; speedup 1.0000x reference)
//
#include <hip/hip_runtime.h>
#include <stdint.h>

// ---------------------------------------------------------------------------
// Model constants
// ---------------------------------------------------------------------------
#define BATCH       64
#define SEQ_LEN     2048
#define D_MODEL     128
#define WIN         64
#define NWIN        64
#define PRED_LEN    4
#define XSTRIDE     2052   // SEQ_LEN + PRED_LEN
#define NTHREADS    1024
#define MAIN_BLOCKS 64
#define WIN_BLOCKS  2048
#define WIN_PER_BLK 2      // 2048 * 2 = 4096 = BATCH*NWIN windows

// LDS pad: force exactly 1 block/CU (160 KiB LDS). Block LDS ~82 KiB ->
// floor(160/82)=1 -> occupancy cap = 16 waves/CU = 4 waves/EU -> the register
// allocator's budget is 128 VGPRs and spilling below that buys NOTHING.
// This is the hardware-enforced replacement for waves_per_eu (which HIP's
// launch_bounds silently overrides - measured no-op in round 5).
#define PAD_FLOATS 18688

// Pin a value into a VGPR (insurance against re-sinking).
#define PIN(x)  asm volatile("" : "+v"(x))
#define PIN4(v) do { PIN(v.x); PIN(v.y); PIN(v.z); PIN(v.w); } while (0)

// Launder a pointer: loads through it are no longer provably invariant, so
// they cannot be rematerialized/sunk across the __syncthreads() inside the
// recurrence loop.
__device__ __forceinline__ const float* launder(const float* p) {
    uintptr_t v = (uintptr_t)p;
    asm volatile("" : "+s"(v));
    return (const float*)v;
}

// ---------------------------------------------------------------------------
// Threefry-2x32 (exact jax implementation)
// ---------------------------------------------------------------------------
__device__ __forceinline__ uint32_t rotl32(uint32_t v, int d) {
    return (v << d) | (v >> (32 - d));
}

__device__ __forceinline__ void threefry2x32(uint32_t k0, uint32_t k1,
                                             uint32_t x0, uint32_t x1,
                                             uint32_t& o0, uint32_t& o1) {
    uint32_t ks0 = k0, ks1 = k1, ks2 = k0 ^ k1 ^ 0x1BD11BDAu;
    x0 += ks0; x1 += ks1;
#define TF_R(r) { x0 += x1; x1 = rotl32(x1, r); x1 ^= x0; }
    TF_R(13) TF_R(15) TF_R(26) TF_R(6)
    x0 += ks1; x1 += ks2 + 1u;
    TF_R(17) TF_R(29) TF_R(16) TF_R(24)
    x0 += ks2; x1 += ks0 + 2u;
    TF_R(13) TF_R(15) TF_R(26) TF_R(6)
    x0 += ks0; x1 += ks1 + 3u;
    TF_R(17) TF_R(29) TF_R(16) TF_R(24)
    x0 += ks1; x1 += ks2 + 4u;
    TF_R(13) TF_R(15) TF_R(26) TF_R(6)
    x0 += ks2; x1 += ks0 + 5u;
#undef TF_R
    o0 = x0; o1 = x1;
}

// ---------------------------------------------------------------------------
// Activations
// ---------------------------------------------------------------------------
__device__ __forceinline__ float sigf(float x) {
    return 1.f / (1.f + __expf(-x));
}
__device__ __forceinline__ float tanhf_(float x) {
    float e = __expf(2.f * x);
    return 1.f - 2.f / (e + 1.f);
}

// ---------------------------------------------------------------------------
// K_init: copy batch_x into strided x_ext workspace
// ---------------------------------------------------------------------------
__global__ void init_kernel(const float* __restrict__ bx, float* __restrict__ xext) {
    int idx = blockIdx.x * 256 + threadIdx.x;
    if (idx < BATCH * SEQ_LEN) {
        int b = idx >> 11;
        int t = idx & 2047;
        xext[(size_t)b * XSTRIDE + t] = bx[idx];
    }
}

// ---------------------------------------------------------------------------
// K0: per-batch mean/std (fp64 accum, ddof=1), threefry starts, Q gather
// ---------------------------------------------------------------------------
__global__ void prep_kernel(const float* __restrict__ xext,
                            int* __restrict__ starts, float* __restrict__ Q,
                            int T, int stepIdx) {
    int b = blockIdx.x;
    int tid = threadIdx.x;
    const float* xb = xext + (size_t)b * XSTRIDE;

    double s = 0.0, s2 = 0.0;
    for (int t = tid; t < T; t += 256) {
        double v = (double)xb[t];
        s += v; s2 += v * v;
    }
    __shared__ double rs[256], rs2[256];
    rs[tid] = s; rs2[tid] = s2;
    __syncthreads();
    for (int off = 128; off > 0; off >>= 1) {
        if (tid < off) { rs[tid] += rs[tid + off]; rs2[tid] += rs2[tid + off]; }
        __syncthreads();
    }
    __shared__ float thr_s;
    if (tid == 0) {
        double mean = rs[0] / (double)T;
        double var = (rs2[0] - (double)T * mean * mean) / (double)(T - 1);
        if (var < 0.0) var = 0.0;
        thr_s = (float)(mean + 1.48 * sqrt(var));
    }
    __syncthreads();

    if (tid < NWIN) {
        // key_i = fold_in(key(42), stepIdx) = threefry(key=(0,42), x=(0,i))
        uint32_t ka, kb;
        threefry2x32(0u, 42u, 0u, (uint32_t)stepIdx, ka, kb);
        // split -> k1=(A0,A1), k2=(B0,B1)
        uint32_t A0, B0, A1, B1;
        threefry2x32(ka, kb, 0u, 2u, A0, B0);
        threefry2x32(ka, kb, 1u, 3u, A1, B1);

        uint32_t idx = (uint32_t)(b * NWIN + tid);
        uint32_t q = idx & 2047u;
        uint32_t h0, h1, l0, l1;
        threefry2x32(A0, A1, q, q + 2048u, h0, h1);
        threefry2x32(B0, B1, q, q + 2048u, l0, l1);
        uint32_t hi = (idx < 2048u) ? h0 : h1;
        uint32_t lo = (idx < 2048u) ? l0 : l1;

        uint32_t span = (uint32_t)(T - WIN);
        uint32_t mult = 65536u % span;
        mult = (mult * mult) % span;
        uint32_t off = ((hi % span) * mult + (lo % span)) % span;
        starts[idx] = (int)off;
        Q[idx] = (xb[off + WIN] > thr_s) ? 1.f : 0.f;
    }
}

// ---------------------------------------------------------------------------
// K1: FUSED main GRU (blocks 0..63) + window GRUs (remaining blocks).
// Thread layout: tid = j*8 + ko; j in [0,128) hidden unit, ko in [0,8)
// k-eighth (16 of 128 k-values).  Thread holds Wh rows (j, j+128, j+256),
// cols [ko*16 .. ko*16+16) = 48 floats register-resident (~90 VGPR total
// demand, under the 128-VGPR budget enforced by the LDS pad -> 1 block/CU).
// k-groups ROTATED by ko: the 8 distinct LDS addresses per ds_read_b128 map
// pairwise onto 4 bank quads -> 2-way conflict = free.  t-loop unrolled by 2
// so the h double-buffer flip is a compile-time +512B immediate.  Own h[j]
// carried in a register.
// ---------------------------------------------------------------------------

// One GRU step: reads h from hp[c] + OFF (LDS), writes new h[j] to WP.
#define GSTEP(OFF, WP, XV)                                                  \
    do {                                                                    \
        float xv_ = (XV);                                                   \
        float ar = 0.f, az = 0.f, an = 0.f;                                 \
        _Pragma("unroll")                                                   \
        for (int c = 0; c < 4; ++c) {                                       \
            float4 hv = *(const float4*)(hp[c] + (OFF));                    \
            ar = fmaf(wr[c].x, hv.x, ar); ar = fmaf(wr[c].y, hv.y, ar);     \
            ar = fmaf(wr[c].z, hv.z, ar); ar = fmaf(wr[c].w, hv.w, ar);     \
            az = fmaf(wz[c].x, hv.x, az); az = fmaf(wz[c].y, hv.y, az);     \
            az = fmaf(wz[c].z, hv.z, az); az = fmaf(wz[c].w, hv.w, az);     \
            an = fmaf(wn[c].x, hv.x, an); an = fmaf(wn[c].y, hv.y, an);     \
            an = fmaf(wn[c].z, hv.z, an); an = fmaf(wn[c].w, hv.w, an);     \
        }                                                                   \
        ar += __shfl_xor(ar, 1); ar += __shfl_xor(ar, 2); ar += __shfl_xor(ar, 4); \
        az += __shfl_xor(az, 1); az += __shfl_xor(az, 2); az += __shfl_xor(az, 4); \
        an += __shfl_xor(an, 1); an += __shfl_xor(an, 2); an += __shfl_xor(an, 4); \
        float r = sigf(fmaf(xv_, wir, br) + ar);                            \
        float z = sigf(fmaf(xv_, wiz, bz) + az);                            \
        float n = tanhf_(fmaf(xv_, win, bin) + r * (an + bhn));             \
        hold = fmaf(z, hold - n, n);                                        \
        if (ko == 0) *(WP) = hold;                                          \
        __syncthreads();                                                    \
    } while (0)

__global__ __launch_bounds__(NTHREADS)
void gru_fused_kernel(const float* __restrict__ xext, float* __restrict__ hstate,
                      const int* __restrict__ starts, float* __restrict__ S,
                      const float* Wh_g_, const float* Wi_g_,
                      const float* bi_g_, const float* bh_g_,
                      const float* Wh_w_, const float* Wi_w_,
                      const float* bi_w_, const float* bh_w_,
                      int L, int initFlag) {
    __shared__ float xsh[XSTRIDE];
    __shared__ float hbuf[2][D_MODEL];   // buf1 = buf0 + 512 bytes
    __shared__ float pad[PAD_FLOATS];    // occupancy clamp: 1 block/CU

    const int tid = threadIdx.x;
    const int j = tid >> 3;
    const int ko = tid & 7;
    const bool isMain = (blockIdx.x < MAIN_BLOCKS);

    // Keep the pad live (branch never taken at runtime; L >= 0 always).
    if (L == -12345) pad[tid] = (float)initFlag;

    // ---- select & launder weight pointers ----
    const float* Wh = launder(isMain ? Wh_g_ : Wh_w_);
    const float* Wi = launder(isMain ? Wi_g_ : Wi_w_);
    const float* bi = launder(isMain ? bi_g_ : bi_w_);
    const float* bh = launder(isMain ? bh_g_ : bh_w_);

    // ---- load weights into registers (rotated k-groups) ----
    float4 wr[4], wz[4], wn[4];
    const int colbase = ko * 16;
#pragma unroll
    for (int c = 0; c < 4; ++c) {
        int p = (c + ko) & 3;
        int col = colbase + p * 4;
        wr[c] = *(const float4*)(Wh + (size_t)(j      ) * 128 + col);
        wz[c] = *(const float4*)(Wh + (size_t)(j + 128) * 128 + col);
        wn[c] = *(const float4*)(Wh + (size_t)(j + 256) * 128 + col);
    }
#pragma unroll
    for (int c = 0; c < 4; ++c) { PIN4(wr[c]); PIN4(wz[c]); PIN4(wn[c]); }

    float wir = Wi[j], wiz = Wi[j + 128], win = Wi[j + 256];
    float br  = bi[j] + bh[j];
    float bz  = bi[j + 128] + bh[j + 128];
    float bin = bi[j + 256], bhn = bh[j + 256];
    PIN(wir); PIN(wiz); PIN(win); PIN(br); PIN(bz); PIN(bin); PIN(bhn);

    // ---- per-thread LDS read pointers (computed once; buf1 via +512 imm) ----
    const char* hp[4];
#pragma unroll
    for (int c = 0; c < 4; ++c) {
        int p = (c + ko) & 3;
        hp[c] = (const char*)&hbuf[0][colbase + p * 4];
    }
    float* wp1 = &hbuf[1][j];   // written by even steps (read buf0)
    float* wp0 = &hbuf[0][j];   // written by odd steps  (read buf1)

    if (isMain) {
        // ---- main GRU: one block per batch element ----
        const int b = blockIdx.x;
        for (int t = tid; t < L; t += NTHREADS)
            xsh[t] = xext[(size_t)b * XSTRIDE + t];
        float h0 = 0.f;
        if (!initFlag) h0 = hstate[b * D_MODEL + j];
        if (tid < D_MODEL)
            hbuf[0][tid] = initFlag ? 0.f : hstate[b * D_MODEL + tid];
        float hold = h0;
        __syncthreads();

        int t = 0;
        for (; t + 1 < L; t += 2) {
            GSTEP(0,   wp1, xsh[t]);
            GSTEP(512, wp0, xsh[t + 1]);
        }
        if (t < L) GSTEP(0, wp1, xsh[t]);
        if (ko == 0) hstate[b * D_MODEL + j] = hold;
    } else {
        // ---- window GRUs: WIN_PER_BLK windows per block, sequentially ----
        const int wb = blockIdx.x - MAIN_BLOCKS;
        for (int w = 0; w < WIN_PER_BLK; ++w) {
            int widx = wb * WIN_PER_BLK + w;
            int b = widx >> 6;
            int st = starts[widx];
            if (tid < WIN) xsh[tid] = xext[(size_t)b * XSTRIDE + st + tid];
            if (tid < D_MODEL) hbuf[0][tid] = 0.f;
            float hold = 0.f;
            __syncthreads();

#pragma unroll 1
            for (int t = 0; t < WIN; t += 2) {
                GSTEP(0,   wp1, xsh[t]);
                GSTEP(512, wp0, xsh[t + 1]);
            }
            if (ko == 0) S[(size_t)widx * D_MODEL + j] = hold;
            __syncthreads();   // before next window rewrites xsh/hbuf
        }
    }
}

// ---------------------------------------------------------------------------
// K3: attention + output.  One wave per batch element.
// ---------------------------------------------------------------------------
__global__ void finalize_kernel(float* __restrict__ xext,
                                const float* __restrict__ hstate,
                                const float* __restrict__ S,
                                const float* __restrict__ Q,
                                const float* __restrict__ Wd, const float* __restrict__ bd,
                                const float* __restrict__ Wc, const float* __restrict__ bc,
                                float* __restrict__ out, int stepIdx) {
    int b = blockIdx.x;
    int m = threadIdx.x;  // 64 threads = 1 wave

    __shared__ float Hs[D_MODEL];
    Hs[m]      = hstate[b * D_MODEL + m];
    Hs[m + 64] = hstate[b * D_MODEL + 64 + m];
    __syncthreads();

    // logit_m = H . S[b,m,:]
    const float* Srow = S + (size_t)(b * NWIN + m) * D_MODEL;
    float acc = 0.f;
#pragma unroll
    for (int jj = 0; jj < D_MODEL; ++jj)
        acc = fmaf(Hs[jj], Srow[jj], acc);

    // softmax over 64 lanes
    float mx = acc;
#pragma unroll
    for (int d = 1; d < 64; d <<= 1) mx = fmaxf(mx, __shfl_xor(mx, d));
    float e = __expf(acc - mx);
    float se = e;
#pragma unroll
    for (int d = 1; d < 64; d <<= 1) se += __shfl_xor(se, d);
    float A = e / se;

    float qa = Q[b * NWIN + m] * A;
#pragma unroll
    for (int d = 1; d < 64; d <<= 1) qa += __shfl_xor(qa, d);

    // o = H . Wd + bd
    float po = Hs[m] * Wd[m] + Hs[m + 64] * Wd[m + 64];
#pragma unroll
    for (int d = 1; d < 64; d <<= 1) po += __shfl_xor(po, d);

    if (m == 0) {
        float o = po + bd[0];
        float u = sigf(fmaf(qa, Wc[0], bc[0]));
        float y = o + u;
        xext[(size_t)b * XSTRIDE + SEQ_LEN + stepIdx] = y;
        out[b * PRED_LEN + stepIdx] = y;                       // output 0: x[:, -4:]
        out[BATCH * PRED_LEN + b * PRED_LEN + stepIdx] = u;    // output 1: us
    }
}

// ---------------------------------------------------------------------------
// kernel_launch
// ---------------------------------------------------------------------------
extern "C" void kernel_launch(void* const* d_in, const int* in_sizes, int n_in,
                              void* d_out, int out_size, void* d_ws, size_t ws_size,
                              hipStream_t stream) {
    const float* batch_x = (const float*)d_in[0];
    const float* Wi_g = (const float*)d_in[4];
    const float* Wh_g = (const float*)d_in[5];
    const float* bi_g = (const float*)d_in[6];
    const float* bh_g = (const float*)d_in[7];
    const float* Wi_w = (const float*)d_in[8];
    const float* Wh_w = (const float*)d_in[9];
    const float* bi_w = (const float*)d_in[10];
    const float* bh_w = (const float*)d_in[11];
    const float* Wd   = (const float*)d_in[12];
    const float* bd   = (const float*)d_in[13];
    const float* Wc   = (const float*)d_in[16];
    const float* bc   = (const float*)d_in[17];
    float* out = (float*)d_out;

    // workspace layout (floats)
    float* ws = (float*)d_ws;
    float* xext   = ws;                                  // 64*2052 = 131328
    float* hstate = xext + BATCH * XSTRIDE;              // 8192
    float* Q      = hstate + BATCH * D_MODEL;            // 4096
    float* S      = Q + BATCH * NWIN;                    // 524288
    int*   starts = (int*)(S + (size_t)BATCH * NWIN * D_MODEL); // 4096 ints

    init_kernel<<<512, 256, 0, stream>>>(batch_x, xext);

    for (int i = 0; i < PRED_LEN; ++i) {
        int T = SEQ_LEN + i;                              // current x length
        int L = (i == 0) ? SEQ_LEN : (SEQ_LEN - 1 + i);   // GRU segment length

        prep_kernel<<<BATCH, 256, 0, stream>>>(xext, starts, Q, T, i);
        gru_fused_kernel<<<MAIN_BLOCKS + WIN_BLOCKS, NTHREADS, 0, stream>>>(
            xext, hstate, starts, S,
            Wh_g, Wi_g, bi_g, bh_g,
            Wh_w, Wi_w, bi_w, bh_w,
            L, (i == 0) ? 1 : 0);
        finalize_kernel<<<BATCH, 64, 0, stream>>>(xext, hstate, S, Q,
                                                  Wd, bd, Wc, bc, out, i);
    }
}